// Round 7
// baseline (678.142 us; speedup 1.0000x reference)
//
#include <hip/hip_runtime.h>
#include <hip/hip_bf16.h>

typedef __bf16 bf16_t;
typedef bf16_t bf16x8 __attribute__((ext_vector_type(8)));
typedef bf16_t bf16x4 __attribute__((ext_vector_type(4)));
typedef short  short4v __attribute__((ext_vector_type(4)));
typedef float  f32x4  __attribute__((ext_vector_type(4)));

#define MFMA16(a,b,c) __builtin_amdgcn_mfma_f32_16x16x32_bf16(a, b, c, 0, 0, 0)

static __device__ inline f32x4 mfma_k16(bf16x4 a, bf16x4 b, f32x4 c) {
#if __has_builtin(__builtin_amdgcn_mfma_f32_16x16x16_bf16)
  return __builtin_amdgcn_mfma_f32_16x16x16_bf16(a, b, c, 0, 0, 0);
#else
  return __builtin_amdgcn_mfma_f32_16x16x16bf16_1k(
      __builtin_bit_cast(short4v, a), __builtin_bit_cast(short4v, b), c, 0, 0, 0);
#endif
}

constexpr int S = 2048, H = 16, Dh = 64;
constexpr int N = H * Dh;   // 1024
constexpr int K = 1024;     // E
constexpr int GRID = 768;   // 3 blocks/CU x 256 CUs == exact co-residency
constexpr float QSCALE = 0.125f * 1.4426950408889634f;  // 1/sqrt(64) * log2(e)

static __device__ inline void load_lds16(const bf16_t* g, bf16_t* l) {
  __builtin_amdgcn_global_load_lds(
      (const __attribute__((address_space(1))) void*)g,
      (__attribute__((address_space(3))) void*)l, 16, 0, 0);
}

static __device__ inline ushort f2bb(float x) {
  bf16_t h = (bf16_t)x;
  return __builtin_bit_cast(ushort, h);
}

// Device-scope grid barrier.  Counter starts as harness poison 0xAAAAAAAA;
// every block CASes it to 0 (exactly one succeeds, and all CASes for barrier
// i happen before any block's arrival at barrier i), then arrives and spins.
// Co-residency of all GRID blocks is guaranteed by __launch_bounds__(256,3)
// (VGPR cap 170 -> 3 waves/SIMD) + 34.8 KB LDS (4 blocks/CU) => no deadlock.
static __device__ inline void grid_barrier(unsigned* C, int tid) {
  __threadfence();
  __syncthreads();
  if (tid == 0) {
    atomicCAS(C, 0xAAAAAAAAu, 0u);
    atomicAdd(C, 1u);
    while (__hip_atomic_load(C, __ATOMIC_ACQUIRE, __HIP_MEMORY_SCOPE_AGENT) < GRID)
      __builtin_amdgcn_s_sleep(1);
  }
  __syncthreads();
  __threadfence();
}

// ---------------------------------------------------------------------------
// One persistent kernel: P1 convert X + transpose W; P2 projection GEMMs;
// P3 flash attention.  Grid barriers between phases (kills inter-kernel gaps).
// ---------------------------------------------------------------------------
__global__ __launch_bounds__(256, 3) void fused(
    const float* __restrict__ q, const float* __restrict__ k,
    const float* __restrict__ v,
    const float* __restrict__ wq, const float* __restrict__ wk,
    const float* __restrict__ wv,
    const float* __restrict__ bq, const float* __restrict__ bk,
    const float* __restrict__ bv,
    bf16_t* __restrict__ xq, bf16_t* __restrict__ xk, bf16_t* __restrict__ xv,
    bf16_t* __restrict__ wtq, bf16_t* __restrict__ wtk, bf16_t* __restrict__ wtv,
    bf16_t* __restrict__ qh, bf16_t* __restrict__ kh, bf16_t* __restrict__ vt,
    unsigned* __restrict__ bar, float* __restrict__ out) {
  __shared__ __align__(16) bf16_t smem[17408];   // 34.8 KB, reused per phase

  int bid = blockIdx.x, tid = threadIdx.x;
  int wave = tid >> 6, lane = tid & 63;
  int lr = lane & 15, lg = lane >> 4;
  int lrow = lane >> 3, lchunk = lane & 7;

  // ========================= P1: prep =========================
  {
    // X fp32 -> bf16: 768 chunks of 16384 elems (64/thread)
    int z = bid >> 8, bb = bid & 255;
    const float* xi = z == 0 ? q : z == 1 ? k : v;
    bf16_t*      xo = z == 0 ? xq : z == 1 ? xk : xv;
    size_t base = (size_t)bb * 16384;
    for (int i = 0; i < 8; ++i) {
      size_t idx = base + (size_t)i * 2048 + tid * 8;
      float4 a = *(const float4*)&xi[idx];
      float4 b = *(const float4*)&xi[idx + 4];
      bf16x8 w;
      w[0] = (bf16_t)a.x; w[1] = (bf16_t)a.y; w[2] = (bf16_t)a.z; w[3] = (bf16_t)a.w;
      w[4] = (bf16_t)b.x; w[5] = (bf16_t)b.y; w[6] = (bf16_t)b.z; w[7] = (bf16_t)b.w;
      *(bf16x8*)&xo[idx] = w;
    }
    // W fp32 [K,N] -> Wt bf16 [N,K]: 768 64x64 tile jobs
    ushort (*tile)[68] = (ushort(*)[68])smem;
    const float* wi = z == 0 ? wq : z == 1 ? wk : wv;
    ushort*      wo = (ushort*)(z == 0 ? wtq : z == 1 ? wtk : wtv);
    int k0 = (bb >> 4) * 64, n0 = (bb & 15) * 64;
    for (int i = 0; i < 4; ++i) {
      int idx4 = (i * 256 + tid) * 4;
      int r = idx4 >> 6, c = idx4 & 63;
      float4 vv = *(const float4*)&wi[(size_t)(k0 + r) * N + n0 + c];
      tile[r][c] = f2bb(vv.x); tile[r][c + 1] = f2bb(vv.y);
      tile[r][c + 2] = f2bb(vv.z); tile[r][c + 3] = f2bb(vv.w);
    }
    __syncthreads();
    for (int i = 0; i < 4; ++i) {
      int idx4 = (i * 256 + tid) * 4;
      int r = idx4 >> 6, c = idx4 & 63;
      ushort4 vv;
      vv.x = tile[c][r]; vv.y = tile[c + 1][r];
      vv.z = tile[c + 2][r]; vv.w = tile[c + 3][r];
      *(ushort4*)&wo[(size_t)(n0 + r) * K + k0 + c] = vv;
    }
  }

  grid_barrier(bar, tid);

  // ========================= P2: projection GEMM =========================
  {
    int mode = bid >> 8, r8 = bid & 255;
    int by = r8 >> 3, bx = r8 & 7;
    const bf16_t* X  = mode == 0 ? xq  : mode == 1 ? xk  : wtv;  // A rows
    const bf16_t* Wt = mode == 0 ? wtq : mode == 1 ? wtk : xv;   // B rows
    const float*  Bi = mode == 0 ? bq  : mode == 1 ? bk  : bv;

    bf16_t (*Ash)[64] = (bf16_t(*)[64])smem;
    bf16_t (*Bsh)[64] = (bf16_t(*)[64])(smem + 8192);
    bf16_t* Cs = smem;                     // 128 x 136 after K-loop

    int m0 = (mode < 2 ? by : bx) * 128;
    int n0 = (mode < 2 ? bx : by) * 128;
    int wm = (wave >> 1) * 64, wn = (wave & 1) * 64;

    f32x4 acc[4][4];
    for (int i = 0; i < 4; ++i)
      for (int j = 0; j < 4; ++j) acc[i][j] = (f32x4){0.f, 0.f, 0.f, 0.f};

    for (int ko = 0; ko < K / 64; ++ko) {
      __syncthreads();
      for (int j = 0; j < 4; ++j) {
        int r = wave * 32 + j * 8 + lrow;
        int gc = (lchunk ^ (r & 7)) * 8;
        load_lds16(&X [(size_t)(m0 + r) * K + ko * 64 + gc], &Ash[r][lchunk * 8]);
        load_lds16(&Wt[(size_t)(n0 + r) * K + ko * 64 + gc], &Bsh[r][lchunk * 8]);
      }
      __syncthreads();
      for (int kk = 0; kk < 2; ++kk) {
        bf16x8 af[4], bfr[4];
        for (int i = 0; i < 4; ++i) {
          int rr = wm + i * 16 + lr;
          af[i] = *(const bf16x8*)&Ash[rr][(((kk << 2) | lg) ^ (rr & 7)) * 8];
        }
        for (int j = 0; j < 4; ++j) {
          int rr = wn + j * 16 + lr;
          bfr[j] = *(const bf16x8*)&Bsh[rr][(((kk << 2) | lg) ^ (rr & 7)) * 8];
        }
        for (int i = 0; i < 4; ++i)
          for (int j = 0; j < 4; ++j)
            acc[i][j] = MFMA16(af[i], bfr[j], acc[i][j]);
      }
    }

    float badd[4][4][4];
    if (mode < 2) {
      float bvv[4];
      for (int j = 0; j < 4; ++j) bvv[j] = Bi[n0 + wn + j * 16 + lr];
      for (int i = 0; i < 4; ++i)
        for (int j = 0; j < 4; ++j)
          for (int r = 0; r < 4; ++r) badd[i][j][r] = bvv[j];
    } else {
      for (int i = 0; i < 4; ++i)
        for (int r = 0; r < 4; ++r) {
          float bm = Bi[m0 + wm + i * 16 + lg * 4 + r];
          for (int j = 0; j < 4; ++j) badd[i][j][r] = bm;
        }
    }

    __syncthreads();
    for (int i = 0; i < 4; ++i)
      for (int j = 0; j < 4; ++j)
        for (int r = 0; r < 4; ++r) {
          float vvv = acc[i][j][r] + badd[i][j][r];
          if (mode == 0) vvv *= QSCALE;
          Cs[(size_t)(wm + i * 16 + lg * 4 + r) * 136 + wn + j * 16 + lr] = (bf16_t)vvv;
        }
    __syncthreads();

    bf16_t* o = mode == 0 ? qh : mode == 1 ? kh : vt;
    for (int p = 0; p < 8; ++p) {
      int idx = p * 256 + tid;
      int row = idx >> 4, ch = idx & 15;
      bf16x8 vv = *(const bf16x8*)&Cs[(size_t)row * 136 + ch * 8];
      size_t dst;
      if (mode < 2) {
        int m_g = m0 + row, n_g = n0 + ch * 8;
        int b = m_g >> 11, s = m_g & 2047;
        int h = n_g >> 6, d = n_g & 63;
        dst = (((size_t)(b * 16 + h) * 2048) + s) * 64 + d;
      } else {
        int w_g = m0 + row, t_g = n0 + ch * 8;
        int b = t_g >> 11, s = t_g & 2047;
        dst = ((size_t)(b * 1024 + w_g)) * 2048 + s;
      }
      *(uint4*)&o[dst] = __builtin_bit_cast(uint4, vv);
    }
  }

  grid_barrier(bar + 64, tid);

  // ========================= P3: flash attention =========================
  if (bid < 512) {
    bf16_t (*kt)[64] = (bf16_t(*)[64])smem;           // K  [sk][d], swizzled
    bf16_t (*vs)[64] = (bf16_t(*)[64])(smem + 4096);  // V^T [d][sk], swizzled

    int bh = bid >> 4;
    int q0 = (bid & 15) * 128 + wave * 32;

    const bf16_t* qg = qh + (size_t)bh * S * Dh;
    const bf16_t* kg = kh + (size_t)bh * S * Dh;
    const bf16_t* vg = vt + (size_t)bh * Dh * S;

    bf16x8 bqf[2][2];
    for (int ms = 0; ms < 2; ++ms)
      for (int kk = 0; kk < 2; ++kk)
        bqf[ms][kk] = *(const bf16x8*)&qg[(size_t)(q0 + ms * 16 + lr) * 64 + kk * 32 + lg * 8];

    bf16x4 ones;
    ones[0] = (bf16_t)1.0f; ones[1] = (bf16_t)1.0f;
    ones[2] = (bf16_t)1.0f; ones[3] = (bf16_t)1.0f;

    f32x4 o_acc[2][4], lacc[2];
    for (int ms = 0; ms < 2; ++ms) {
      lacc[ms] = (f32x4){0.f, 0.f, 0.f, 0.f};
      for (int t = 0; t < 4; ++t) o_acc[ms][t] = (f32x4){0.f, 0.f, 0.f, 0.f};
    }

    // loop-invariant swizzled fragment offsets (element units)
    int akoff[2], bvoff[4];
    for (int kk = 0; kk < 2; ++kk)
      akoff[kk] = lr * 64 + (((kk << 2) | lg) ^ (lr & 7)) * 8;
    for (int t = 0; t < 4; ++t)
      bvoff[t] = lr * 64 + (((t * 2 + (lg >> 1)) ^ (lr & 7)) * 8) + (lg & 1) * 4;

    for (int it = 0; it < S / 64; ++it) {
      int sk0 = it * 64;
      __syncthreads();
      for (int j = 0; j < 2; ++j) {
        int r = wave * 16 + j * 8 + lrow;
        int gc = (lchunk ^ (r & 7)) * 8;
        load_lds16(&kg[(size_t)(sk0 + r) * 64 + gc], &kt[r][lchunk * 8]);
        load_lds16(&vg[(size_t)r * S + sk0 + gc], &vs[r][lchunk * 8]);
      }
      __syncthreads();

      bf16x8 ak[4][2];
      for (int t = 0; t < 4; ++t)
        for (int kk = 0; kk < 2; ++kk)
          ak[t][kk] = *(const bf16x8*)&((bf16_t*)kt)[t * 1024 + akoff[kk]];
      bf16x4 bv[4][4];
      for (int t = 0; t < 4; ++t)
        for (int dt = 0; dt < 4; ++dt)
          bv[t][dt] = *(const bf16x4*)&((bf16_t*)vs)[dt * 1024 + bvoff[t]];

      for (int ms = 0; ms < 2; ++ms) {
        f32x4 st[4];
        for (int t = 0; t < 4; ++t) st[t] = (f32x4){0.f, 0.f, 0.f, 0.f};
        for (int t = 0; t < 4; ++t)
          for (int kk = 0; kk < 2; ++kk)
            st[t] = MFMA16(ak[t][kk], bqf[ms][kk], st[t]);

        bf16x4 pa[4];
        for (int t = 0; t < 4; ++t)
          for (int r = 0; r < 4; ++r)
            pa[t][r] = (bf16_t)__builtin_amdgcn_exp2f(st[t][r]);

        for (int t = 0; t < 4; ++t) {
          for (int dt = 0; dt < 4; ++dt)
            o_acc[ms][dt] = mfma_k16(pa[t], bv[t][dt], o_acc[ms][dt]);
          lacc[ms] = mfma_k16(pa[t], ones, lacc[ms]);
        }
      }
    }

    int b = bh >> 4, h = bh & 15;
    for (int ms = 0; ms < 2; ++ms)
      for (int r = 0; r < 4; ++r) {
        float inv = 1.f / lacc[ms][r];
        int s_row = q0 + ms * 16 + lg * 4 + r;
        size_t base = ((size_t)(b * S + s_row)) * 1024 + h * 64;
        for (int dt = 0; dt < 4; ++dt)
          out[base + dt * 16 + lr] = o_acc[ms][dt][r] * inv;
      }
  }
}

// ---------------------------------------------------------------------------
extern "C" void kernel_launch(void* const* d_in, const int* in_sizes, int n_in,
                              void* d_out, int out_size, void* d_ws, size_t ws_size,
                              hipStream_t stream) {
  const float* q  = (const float*)d_in[0];
  const float* k  = (const float*)d_in[1];
  const float* v  = (const float*)d_in[2];
  const float* wq = (const float*)d_in[3];
  const float* bq = (const float*)d_in[4];
  const float* wk = (const float*)d_in[5];
  const float* bk = (const float*)d_in[6];
  const float* wv = (const float*)d_in[7];
  const float* bv = (const float*)d_in[8];

  bf16_t* ws  = (bf16_t*)d_ws;
  constexpr size_t MW = (size_t)1 << 20;
  constexpr size_t MX = (size_t)4096 * 1024;
  bf16_t* wtq = ws;
  bf16_t* wtk = wtq + MW;
  bf16_t* wtv = wtk + MW;
  bf16_t* xq  = wtv + MW;
  bf16_t* xk  = xq + MX;
  bf16_t* xv  = xk + MX;
  bf16_t* qhd = xv + MX;
  bf16_t* khd = qhd + MX;
  bf16_t* vtd = khd + MX;
  unsigned* bar = (unsigned*)(vtd + MX);   // two counters, 256 B apart
  float* out  = (float*)d_out;

  fused<<<GRID, 256, 0, stream>>>(q, k, v, wq, wk, wv, bq, bk, bv,
                                  xq, xk, xv, wtq, wtk, wtv,
                                  qhd, khd, vtd, bar, out);
}

// Round 10
// 206.037 us; speedup vs baseline: 3.2914x; 3.2914x over previous
//
#include <hip/hip_runtime.h>
#include <hip/hip_bf16.h>

typedef __bf16 bf16_t;
typedef bf16_t bf16x8 __attribute__((ext_vector_type(8)));
typedef bf16_t bf16x4 __attribute__((ext_vector_type(4)));
typedef short  short4v __attribute__((ext_vector_type(4)));
typedef float  f32x4  __attribute__((ext_vector_type(4)));

#define MFMA16(a,b,c) __builtin_amdgcn_mfma_f32_16x16x32_bf16(a, b, c, 0, 0, 0)

static __device__ inline f32x4 mfma_k16(bf16x4 a, bf16x4 b, f32x4 c) {
#if __has_builtin(__builtin_amdgcn_mfma_f32_16x16x16_bf16)
  return __builtin_amdgcn_mfma_f32_16x16x16_bf16(a, b, c, 0, 0, 0);
#else
  return __builtin_amdgcn_mfma_f32_16x16x16bf16_1k(
      __builtin_bit_cast(short4v, a), __builtin_bit_cast(short4v, b), c, 0, 0, 0);
#endif
}

constexpr int S = 2048, H = 16, Dh = 64;
constexpr int N = H * Dh;   // 1024
constexpr int K = 1024;     // E
constexpr float QSCALE = 0.125f * 1.4426950408889634f;  // 1/sqrt(64) * log2(e)

static __device__ inline void load_lds16(const bf16_t* g, bf16_t* l) {
  __builtin_amdgcn_global_load_lds(
      (const __attribute__((address_space(1))) void*)g,
      (__attribute__((address_space(3))) void*)l, 16, 0, 0);
}

static __device__ inline ushort f2bb(float x) {
  bf16_t h = (bf16_t)x;
  return __builtin_bit_cast(ushort, h);
}

// ---------------------------------------------------------------------------
// prep: blocks 0..6143 convert X fp32->bf16; blocks 6144..6911 transpose W.
// (R6 verbatim)
// ---------------------------------------------------------------------------
__global__ __launch_bounds__(256) void prep(
    const float* __restrict__ q, const float* __restrict__ k,
    const float* __restrict__ v,
    const float* __restrict__ wq, const float* __restrict__ wk,
    const float* __restrict__ wv,
    bf16_t* __restrict__ xq, bf16_t* __restrict__ xk, bf16_t* __restrict__ xv,
    bf16_t* __restrict__ wtq, bf16_t* __restrict__ wtk, bf16_t* __restrict__ wtv) {
  __shared__ ushort tile[64][68];
  int bx = blockIdx.x, t = threadIdx.x;
  if (bx < 6144) {
    int z = bx >> 11, bb = bx & 2047;
    const float* xi = z == 0 ? q : z == 1 ? k : v;
    bf16_t*      xo = z == 0 ? xq : z == 1 ? xk : xv;
    size_t idx = ((size_t)bb * 256 + t) * 8;
    float4 a = *(const float4*)&xi[idx];
    float4 b = *(const float4*)&xi[idx + 4];
    bf16x8 w;
    w[0] = (bf16_t)a.x; w[1] = (bf16_t)a.y; w[2] = (bf16_t)a.z; w[3] = (bf16_t)a.w;
    w[4] = (bf16_t)b.x; w[5] = (bf16_t)b.y; w[6] = (bf16_t)b.z; w[7] = (bf16_t)b.w;
    *(bf16x8*)&xo[idx] = w;
  } else {
    int zz = bx - 6144;
    int z = zz >> 8, bb = zz & 255;
    const float* wi = z == 0 ? wq : z == 1 ? wk : wv;
    ushort*      wo = (ushort*)(z == 0 ? wtq : z == 1 ? wtk : wtv);
    int k0 = (bb >> 4) * 64, n0 = (bb & 15) * 64;
    for (int i = 0; i < 4; ++i) {
      int idx4 = (i * 256 + t) * 4;
      int r = idx4 >> 6, c = idx4 & 63;
      float4 vv = *(const float4*)&wi[(size_t)(k0 + r) * N + n0 + c];
      tile[r][c] = f2bb(vv.x); tile[r][c + 1] = f2bb(vv.y);
      tile[r][c + 2] = f2bb(vv.z); tile[r][c + 3] = f2bb(vv.w);
    }
    __syncthreads();
    for (int i = 0; i < 4; ++i) {
      int idx4 = (i * 256 + t) * 4;
      int r = idx4 >> 6, c = idx4 & 63;
      ushort4 vv;
      vv.x = tile[c][r]; vv.y = tile[c + 1][r];
      vv.z = tile[c + 2][r]; vv.w = tile[c + 3][r];
      *(ushort4*)&wo[(size_t)(n0 + r) * K + k0 + c] = vv;
    }
  }
}

// ---------------------------------------------------------------------------
// Projection GEMM (R6 verbatim: m97 2-barrier DMA staging -- the VERIFIED
// shape -- XOR swizzle, LDS-staged coalesced epilogue).
// ---------------------------------------------------------------------------
__global__ __launch_bounds__(256) void proj_gemm(
    const bf16_t* __restrict__ xq, const bf16_t* __restrict__ xk,
    const bf16_t* __restrict__ xv,
    const bf16_t* __restrict__ wtq, const bf16_t* __restrict__ wtk,
    const bf16_t* __restrict__ wtv,
    const float* __restrict__ bq, const float* __restrict__ bk,
    const float* __restrict__ bv,
    bf16_t* __restrict__ qh, bf16_t* __restrict__ kh, bf16_t* __restrict__ vt) {
  int mode = blockIdx.z;
  const bf16_t* X  = mode == 0 ? xq  : mode == 1 ? xk  : wtv;  // A rows
  const bf16_t* Wt = mode == 0 ? wtq : mode == 1 ? wtk : xv;   // B rows
  const float*  Bi = mode == 0 ? bq  : mode == 1 ? bk  : bv;

  __shared__ __align__(16) bf16_t smem[17408];   // 34.8 KB
  bf16_t (*Ash)[64] = (bf16_t(*)[64])smem;
  bf16_t (*Bsh)[64] = (bf16_t(*)[64])(smem + 8192);
  bf16_t* Cs = smem;

  int tid = threadIdx.x;
  int wave = tid >> 6, lane = tid & 63;
  int lr = lane & 15, lg = lane >> 4;
  int lrow = lane >> 3, lchunk = lane & 7;
  int m0 = (mode < 2 ? blockIdx.y : blockIdx.x) * 128;
  int n0 = (mode < 2 ? blockIdx.x : blockIdx.y) * 128;
  int wm = (wave >> 1) * 64, wn = (wave & 1) * 64;

  f32x4 acc[4][4];
  for (int i = 0; i < 4; ++i)
    for (int j = 0; j < 4; ++j) acc[i][j] = (f32x4){0.f, 0.f, 0.f, 0.f};

  for (int ko = 0; ko < K / 64; ++ko) {
    __syncthreads();
    for (int j = 0; j < 4; ++j) {
      int r = wave * 32 + j * 8 + lrow;
      int gc = (lchunk ^ (r & 7)) * 8;
      load_lds16(&X [(size_t)(m0 + r) * K + ko * 64 + gc], &Ash[r][lchunk * 8]);
      load_lds16(&Wt[(size_t)(n0 + r) * K + ko * 64 + gc], &Bsh[r][lchunk * 8]);
    }
    __syncthreads();
    for (int kk = 0; kk < 2; ++kk) {
      bf16x8 af[4], bfr[4];
      for (int i = 0; i < 4; ++i) {
        int rr = wm + i * 16 + lr;
        af[i] = *(const bf16x8*)&Ash[rr][(((kk << 2) | lg) ^ (rr & 7)) * 8];
      }
      for (int j = 0; j < 4; ++j) {
        int rr = wn + j * 16 + lr;
        bfr[j] = *(const bf16x8*)&Bsh[rr][(((kk << 2) | lg) ^ (rr & 7)) * 8];
      }
      for (int i = 0; i < 4; ++i)
        for (int j = 0; j < 4; ++j)
          acc[i][j] = MFMA16(af[i], bfr[j], acc[i][j]);
    }
  }

  float badd[4][4][4];
  if (mode < 2) {
    float bvv[4];
    for (int j = 0; j < 4; ++j) bvv[j] = Bi[n0 + wn + j * 16 + lr];
    for (int i = 0; i < 4; ++i)
      for (int j = 0; j < 4; ++j)
        for (int r = 0; r < 4; ++r) badd[i][j][r] = bvv[j];
  } else {
    for (int i = 0; i < 4; ++i)
      for (int r = 0; r < 4; ++r) {
        float bm = Bi[m0 + wm + i * 16 + lg * 4 + r];
        for (int j = 0; j < 4; ++j) badd[i][j][r] = bm;
      }
  }

  __syncthreads();
  for (int i = 0; i < 4; ++i)
    for (int j = 0; j < 4; ++j)
      for (int r = 0; r < 4; ++r) {
        float vvv = acc[i][j][r] + badd[i][j][r];
        if (mode == 0) vvv *= QSCALE;
        Cs[(size_t)(wm + i * 16 + lg * 4 + r) * 136 + wn + j * 16 + lr] = (bf16_t)vvv;
      }
  __syncthreads();

  bf16_t* o = mode == 0 ? qh : mode == 1 ? kh : vt;
  for (int p = 0; p < 8; ++p) {
    int idx = p * 256 + tid;
    int row = idx >> 4, ch = idx & 15;
    bf16x8 vv = *(const bf16x8*)&Cs[(size_t)row * 136 + ch * 8];
    size_t dst;
    if (mode < 2) {
      int m_g = m0 + row, n_g = n0 + ch * 8;
      int b = m_g >> 11, s = m_g & 2047;
      int h = n_g >> 6, d = n_g & 63;
      dst = (((size_t)(b * 16 + h) * 2048) + s) * 64 + d;
    } else {
      int w_g = m0 + row, t_g = n0 + ch * 8;
      int b = t_g >> 11, s = t_g & 2047;
      dst = ((size_t)(b * 1024 + w_g)) * 2048 + s;
    }
    *(uint4*)&o[dst] = __builtin_bit_cast(uint4, vv);
  }
}

// ---------------------------------------------------------------------------
// Flash attention v4.2: EXACT R6 v4 compute dataflow, with REGISTER-PREFETCH
// double-buffering instead of LDS-DMA dbuf (R8/R9 post-mortem: DMA dbuf races
// -- cross-wave LDS visibility of global_load_lds is only guaranteed in the
// stage->barrier->consume shape).  Pattern: global->VGPR loads for tile i+1
// issued before computing tile i; LDS filled via ds_write_b128 (lgkm-tracked,
// drained at barriers by construction -> race-free); single LDS buffer.
// ---------------------------------------------------------------------------
__global__ __launch_bounds__(256) void attn(
    const bf16_t* __restrict__ qh, const bf16_t* __restrict__ kh,
    const bf16_t* __restrict__ vt, float* __restrict__ out) {
  __shared__ __align__(16) bf16_t smem[8192];    // kt: 0..4095, vs: 4096..8191
  bf16_t* kt = smem;
  bf16_t* vs = smem + 4096;

  int tid = threadIdx.x, wave = tid >> 6, lane = tid & 63;
  int lr = lane & 15, lg = lane >> 4;
  int lrow = lane >> 3, lchunk = lane & 7;
  int bh = blockIdx.y;
  int q0 = blockIdx.x * 128 + wave * 32;

  const bf16_t* qg = qh + (size_t)bh * S * Dh;
  const bf16_t* kg = kh + (size_t)bh * S * Dh;
  const bf16_t* vg = vt + (size_t)bh * Dh * S;

  bf16x8 bqf[2][2];
  for (int ms = 0; ms < 2; ++ms)
    for (int kk = 0; kk < 2; ++kk)
      bqf[ms][kk] = *(const bf16x8*)&qg[(size_t)(q0 + ms * 16 + lr) * 64 + kk * 32 + lg * 8];

  bf16x4 ones;
  ones[0] = (bf16_t)1.0f; ones[1] = (bf16_t)1.0f;
  ones[2] = (bf16_t)1.0f; ones[3] = (bf16_t)1.0f;

  f32x4 o_acc[2][4], lacc[2];
  for (int ms = 0; ms < 2; ++ms) {
    lacc[ms] = (f32x4){0.f, 0.f, 0.f, 0.f};
    for (int t = 0; t < 4; ++t) o_acc[ms][t] = (f32x4){0.f, 0.f, 0.f, 0.f};
  }

  // staging geometry: wave covers rows wave*16 .. wave*16+15 (two row-groups)
  int srow0 = wave * 16 + lrow;
  int srow1 = srow0 + 8;
  int sgc = (lchunk ^ (srow0 & 7)) * 8;   // (srow1&7)==(srow0&7)
  // LDS element offsets for this thread's two 16B slots per matrix
  int ld0 = srow0 * 64 + lchunk * 8;
  int ld1 = srow1 * 64 + lchunk * 8;

  // prologue: prefetch tile 0 into VGPRs
  uint4 kr0 = *(const uint4*)&kg[(size_t)srow0 * 64 + sgc];
  uint4 kr1 = *(const uint4*)&kg[(size_t)srow1 * 64 + sgc];
  uint4 vr0 = *(const uint4*)&vg[(size_t)srow0 * S + sgc];
  uint4 vr1 = *(const uint4*)&vg[(size_t)srow1 * S + sgc];

  constexpr int NIT = S / 64;
  for (int it = 0; it < NIT; ++it) {
    __syncthreads();                     // prev iter's LDS reads retired
    *(uint4*)&kt[ld0] = kr0;             // waits vmcnt for OWN loads only
    *(uint4*)&kt[ld1] = kr1;
    *(uint4*)&vs[ld0] = vr0;
    *(uint4*)&vs[ld1] = vr1;
    if (it + 1 < NIT) {                  // prefetch tile i+1; lands during compute
      int sk1 = (it + 1) * 64;
      kr0 = *(const uint4*)&kg[(size_t)(sk1 + srow0) * 64 + sgc];
      kr1 = *(const uint4*)&kg[(size_t)(sk1 + srow1) * 64 + sgc];
      vr0 = *(const uint4*)&vg[(size_t)srow0 * S + sk1 + sgc];
      vr1 = *(const uint4*)&vg[(size_t)srow1 * S + sk1 + sgc];
    }
    __syncthreads();                     // ds_writes visible to all waves

    // R6 v4 compute, verbatim
    bf16x8 ak[4][2];
    for (int t = 0; t < 4; ++t)
      for (int kk = 0; kk < 2; ++kk)
        ak[t][kk] = *(const bf16x8*)
            &kt[(t * 16 + lr) * 64 + ((kk * 4 + lg) ^ (lr & 7)) * 8];
    bf16x4 bv[4][4];
    for (int t = 0; t < 4; ++t)
      for (int dt = 0; dt < 4; ++dt)
        bv[t][dt] = *(const bf16x4*)
            &vs[(dt * 16 + lr) * 64 + (((t * 2 + (lg >> 1)) ^ (lr & 7)) * 8) + (lg & 1) * 4];

    for (int ms = 0; ms < 2; ++ms) {
      f32x4 st[4];
      for (int t = 0; t < 4; ++t) st[t] = (f32x4){0.f, 0.f, 0.f, 0.f};
      for (int t = 0; t < 4; ++t)
        for (int kk = 0; kk < 2; ++kk)
          st[t] = MFMA16(ak[t][kk], bqf[ms][kk], st[t]);

      bf16x4 pa[4];
      for (int t = 0; t < 4; ++t)
        for (int r = 0; r < 4; ++r)
          pa[t][r] = (bf16_t)__builtin_amdgcn_exp2f(st[t][r]);

      for (int t = 0; t < 4; ++t) {
        for (int dt = 0; dt < 4; ++dt)
          o_acc[ms][dt] = mfma_k16(pa[t], bv[t][dt], o_acc[ms][dt]);
        lacc[ms] = mfma_k16(pa[t], ones, lacc[ms]);
      }
    }
  }

  int b = bh >> 4, h = bh & 15;
  for (int ms = 0; ms < 2; ++ms)
    for (int r = 0; r < 4; ++r) {
      float inv = 1.f / lacc[ms][r];
      int s_row = q0 + ms * 16 + lg * 4 + r;
      size_t base = ((size_t)(b * S + s_row)) * 1024 + h * 64;
      for (int dt = 0; dt < 4; ++dt)
        out[base + dt * 16 + lr] = o_acc[ms][dt][r] * inv;
    }
}

// ---------------------------------------------------------------------------
extern "C" void kernel_launch(void* const* d_in, const int* in_sizes, int n_in,
                              void* d_out, int out_size, void* d_ws, size_t ws_size,
                              hipStream_t stream) {
  const float* q  = (const float*)d_in[0];
  const float* k  = (const float*)d_in[1];
  const float* v  = (const float*)d_in[2];
  const float* wq = (const float*)d_in[3];
  const float* bq = (const float*)d_in[4];
  const float* wk = (const float*)d_in[5];
  const float* bk = (const float*)d_in[6];
  const float* wv = (const float*)d_in[7];
  const float* bv = (const float*)d_in[8];

  bf16_t* ws  = (bf16_t*)d_ws;
  constexpr size_t MW = (size_t)1 << 20;
  constexpr size_t MX = (size_t)4096 * 1024;
  bf16_t* wtq = ws;
  bf16_t* wtk = wtq + MW;
  bf16_t* wtv = wtk + MW;
  bf16_t* xq  = wtv + MW;
  bf16_t* xk  = xq + MX;
  bf16_t* xv  = xk + MX;
  bf16_t* qhd = xv + MX;
  bf16_t* khd = qhd + MX;
  bf16_t* vtd = khd + MX;
  float* out  = (float*)d_out;

  prep<<<6912, 256, 0, stream>>>(q, k, v, wq, wk, wv,
                                 xq, xk, xv, wtq, wtk, wtv);
  proj_gemm<<<dim3(8, 32, 3), 256, 0, stream>>>(xq, xk, xv, wtq, wtk, wtv,
                                                bq, bk, bv, qhd, khd, vtd);
  attn<<<dim3(16, 32), 256, 0, stream>>>(qhd, khd, vtd, out);
}